// Round 3
// 871.187 us; speedup vs baseline: 1.0563x; 1.0563x over previous
//
#include <hip/hip_runtime.h>
#include <cstdint>

typedef __bf16 bf16;
typedef __bf16 bf16x2 __attribute__((ext_vector_type(2)));
typedef __bf16 bf16x4 __attribute__((ext_vector_type(4)));
typedef __bf16 bf16x8 __attribute__((ext_vector_type(8)));
typedef float  f32x4  __attribute__((ext_vector_type(4)));

#define DIM   4096
#define NH    32
#define NKV   8
#define HD    128
#define BATCH 2
#define SEQ   2048
#define NTOK  (BATCH * SEQ)   // 4096
#define QKVN  6144            // NH*HD + 2*NKV*HD
#define KCOFF 4096            // k column offset in qkv buffer
#define VCOFF 5120            // v column offset
#define NEG_BIG (-1e30f)

// async global->LDS, 16B per lane; LDS dest is wave-uniform base + lane*16
#define GLL16(gp, lp)                                                          \
  __builtin_amdgcn_global_load_lds(                                            \
      (__attribute__((address_space(1))) uint32_t*)(gp),                       \
      (__attribute__((address_space(3))) uint32_t*)(lp), 16, 0, 0)

// ---------------------------------------------------------------------------
// fused wq/wk/wv transpose+convert into concatenated wT[6144][4096]
__global__ __launch_bounds__(256) void transpose_cvt3(const float* __restrict__ wq,
                                                      const float* __restrict__ wk,
                                                      const float* __restrict__ wv,
                                                      bf16* __restrict__ out) {
  __shared__ float t[32][33];
  const int tx = threadIdx.x, ty = threadIdx.y;
  const int n0 = blockIdx.x * 32;  // col in concat [0,6144)
  const int k0 = blockIdx.y * 32;  // row (K dim)
  const float* src; int c0, C;
  if (n0 < 4096)      { src = wq; c0 = n0;        C = 4096; }
  else if (n0 < 5120) { src = wk; c0 = n0 - 4096; C = 1024; }
  else                { src = wv; c0 = n0 - 5120; C = 1024; }
#pragma unroll
  for (int yy = 0; yy < 32; yy += 8)
    t[ty + yy][tx] = src[(size_t)(k0 + ty + yy) * C + c0 + tx];
  __syncthreads();
#pragma unroll
  for (int yy = 0; yy < 32; yy += 8)
    out[(size_t)(n0 + ty + yy) * DIM + k0 + tx] = (bf16)t[tx][ty + yy];
}

// transpose + convert: in[R][C] f32 -> out[C][R] bf16 (for wo)
__global__ __launch_bounds__(256) void transpose_cvt(const float* __restrict__ in,
                                                     bf16* __restrict__ out,
                                                     int R, int C) {
  __shared__ float t[32][33];
  const int tx = threadIdx.x, ty = threadIdx.y;
  const int gx = blockIdx.x * 32, gy = blockIdx.y * 32;
#pragma unroll
  for (int yy = 0; yy < 32; yy += 8)
    t[ty + yy][tx] = in[(size_t)(gy + ty + yy) * C + gx + tx];
  __syncthreads();
#pragma unroll
  for (int yy = 0; yy < 32; yy += 8)
    out[(size_t)(gx + ty + yy) * R + gy + tx] = (bf16)t[tx][ty + yy];
}

// elementwise fp32 -> bf16, 4 per thread
__global__ __launch_bounds__(256) void cvt_f32_bf16(const float* __restrict__ in,
                                                    bf16* __restrict__ out) {
  size_t i = ((size_t)blockIdx.x * 256 + threadIdx.x) * 4;
  f32x4 v = *(const f32x4*)(in + i);
  bf16x4 o;
  o[0] = (bf16)v[0]; o[1] = (bf16)v[1]; o[2] = (bf16)v[2]; o[3] = (bf16)v[3];
  *(bf16x4*)(out + i) = o;
}

// ---------------------------------------------------------------------------
// 256x256 8-wave GEMM, BK=64, 4 phases/K-tile, counted vmcnt (never 0 in
// steady state), XOR-swizzled LDS (conflict-free ds_read_b128), setprio
// around MFMA clusters. C[M][N] = A[M][K] @ BT[N][K]^T.
//
// LDS: [buf(2)][A/B(2)][khalf(2)][256 rows x 32 bf16] = 128 KiB.
// Swizzle: within each 64B row of a half-tile, 16B chunk p holds global
// chunk p ^ ((row>>1)&3)  (2 lanes/bank on frag reads = free).
// Staging: half-tile = 256x32 = 1024 chunks; thread stages chunks tid and
// 512+tid (same swizzle for both since rows differ by 128 == 0 mod 4).
//
// Per K-tile t (buf c=t&1, other o):
//  P1: read A(m0,k0)x4 + B(:,k0)x4 ; stage Ak1(t+1)->o ; bar; lgkm0; 16 MFMA; bar
//  P2: read A(m1,k0)x4             ; stage Bk1(t+1)->o ; bar; lgkm0; 16 MFMA; bar
//  P3: read A(m0,k1)x4 + B(:,k1)x4 ; stage Ak0(t+2)->c ; bar; lgkm0; 16 MFMA; bar
//  P4: read A(m1,k1)x4             ; stage Bk0(t+2)->c ; vmcnt(4); bar; lgkm0; 16 MFMA; bar
// Every LDS overwrite is >=1 phase-end barrier after the last read of that
// region completed (reads retire before the barrier via the post-barrier
// lgkmcnt(0) preceding the MFMAs). vmcnt(4) at P4 retires tile t+1 fully
// while leaving {Ak0(t+2),Bk0(t+2)} in flight across the tile boundary.
#define STG(bufsel, ab, kh, tile, gp)                                          \
  do {                                                                         \
    bf16* lh_ = lds + (((bufsel) * 4 + (ab) * 2 + (kh)) * 8192);               \
    const bf16* gr_ = (gp) + (size_t)(tile) * 64 + (kh) * 32 + sgc * 8;        \
    GLL16(gr_ + (size_t)sr0 * K, lh_ + (w << 6) * 8);                          \
    GLL16(gr_ + (size_t)sr1 * K, lh_ + (512 + (w << 6)) * 8);                  \
  } while (0)

#define FRAG(bufsel, ab, kh, row)                                              \
  (*(const bf16x8*)(lds + (((bufsel) * 4 + (ab) * 2 + (kh)) * 8192) +          \
                    (row) * 32 + ((quad ^ (((row) >> 1) & 3)) << 3)))

#define MFMA_CLUSTER(mh, AFR)                                                  \
  do {                                                                         \
    __builtin_amdgcn_s_setprio(1);                                             \
    _Pragma("unroll")                                                          \
    for (int mf = 0; mf < 4; ++mf)                                             \
      _Pragma("unroll")                                                        \
      for (int nf = 0; nf < 4; ++nf)                                           \
        acc[mh][mf][nf] = __builtin_amdgcn_mfma_f32_16x16x32_bf16(             \
            AFR[mf], bF[nf], acc[mh][mf][nf], 0, 0, 0);                        \
    __builtin_amdgcn_s_setprio(0);                                             \
  } while (0)

template <bool OUTF32>
__global__ __launch_bounds__(512, 2) void gemm256(const bf16* __restrict__ A,
                                                  const bf16* __restrict__ BT,
                                                  void* __restrict__ Cout,
                                                  int M, int N, int K) {
  __shared__ __align__(16) bf16 lds[65536];  // 128 KiB
  const int tid = threadIdx.x;
  const int w = tid >> 6, lane = tid & 63;
  const int quad = lane >> 4, lq = lane & 15;
  const int wmi = w >> 2, wni = w & 3;  // 2 (M) x 4 (N) waves

  // bijective XCD swizzle on flat 1-D grid (nwg % 8 == 0 here: 384, 256)
  const int nbx = N >> 8;
  const int nwg = (int)gridDim.x;
  const int flat = (int)blockIdx.x;
  const int swz = (flat & 7) * (nwg >> 3) + (flat >> 3);
  const int bm = (swz / nbx) << 8, bn = (swz % nbx) << 8;

  const bf16* aB = A + (size_t)bm * K;
  const bf16* bB = BT + (size_t)bn * K;
  const int NT = K >> 6;

  // staging geometry (chunk c = l*512 + tid; row = c>>2; swizzled chunk pos)
  const int sgc = (tid & 3) ^ ((tid >> 3) & 3);
  const int sr0 = tid >> 2, sr1 = sr0 + 128;
  const int am = wmi * 128, bnr = wni * 64;

  f32x4 acc[2][4][4] = {};

  // ---- prologue: tile0 complete + {Ak0,Bk0}(1) in flight ----
  STG(0, 0, 0, 0, aB); STG(0, 1, 0, 0, bB);
  STG(0, 0, 1, 0, aB); STG(0, 1, 1, 0, bB);
  STG(1, 0, 0, 1, aB); STG(1, 1, 0, 1, bB);
  asm volatile("s_waitcnt vmcnt(4)" ::: "memory");
  __builtin_amdgcn_s_barrier();

  for (int t = 0; t < NT; ++t) {
    const int cb = t & 1, ob = cb ^ 1;
    bf16x8 aF[4], bF[4], a2[4];

    // ---- phase 1: (m0, k0) ----
#pragma unroll
    for (int f = 0; f < 4; ++f) aF[f] = FRAG(cb, 0, 0, am + f * 16 + lq);
#pragma unroll
    for (int f = 0; f < 4; ++f) bF[f] = FRAG(cb, 1, 0, bnr + f * 16 + lq);
    if (t + 1 < NT) STG(ob, 0, 1, t + 1, aB);
    __builtin_amdgcn_s_barrier();
    asm volatile("s_waitcnt lgkmcnt(0)" ::: "memory");
    MFMA_CLUSTER(0, aF);
    __builtin_amdgcn_s_barrier();

    // ---- phase 2: (m1, k0) ----
#pragma unroll
    for (int f = 0; f < 4; ++f) a2[f] = FRAG(cb, 0, 0, am + 64 + f * 16 + lq);
    if (t + 1 < NT) STG(ob, 1, 1, t + 1, bB);
    __builtin_amdgcn_s_barrier();
    asm volatile("s_waitcnt lgkmcnt(0)" ::: "memory");
    MFMA_CLUSTER(1, a2);
    __builtin_amdgcn_s_barrier();

    // ---- phase 3: (m0, k1) ----
    if (t == NT - 1) asm volatile("s_waitcnt vmcnt(0)" ::: "memory");
#pragma unroll
    for (int f = 0; f < 4; ++f) aF[f] = FRAG(cb, 0, 1, am + f * 16 + lq);
#pragma unroll
    for (int f = 0; f < 4; ++f) bF[f] = FRAG(cb, 1, 1, bnr + f * 16 + lq);
    if (t + 2 < NT) STG(cb, 0, 0, t + 2, aB);
    __builtin_amdgcn_s_barrier();
    asm volatile("s_waitcnt lgkmcnt(0)" ::: "memory");
    MFMA_CLUSTER(0, aF);
    __builtin_amdgcn_s_barrier();

    // ---- phase 4: (m1, k1) ----
#pragma unroll
    for (int f = 0; f < 4; ++f) a2[f] = FRAG(cb, 0, 1, am + 64 + f * 16 + lq);
    if (t + 2 < NT) STG(cb, 1, 0, t + 2, bB);
    asm volatile("s_waitcnt vmcnt(4)" ::: "memory");
    __builtin_amdgcn_s_barrier();
    asm volatile("s_waitcnt lgkmcnt(0)" ::: "memory");
    MFMA_CLUSTER(1, a2);
    __builtin_amdgcn_s_barrier();
  }

  // ---- epilogue: direct stores (16-lane contiguous segments per quad) ----
#pragma unroll
  for (int mh = 0; mh < 2; ++mh)
#pragma unroll
    for (int mf = 0; mf < 4; ++mf) {
      const size_t rbase =
          (size_t)(bm + am + mh * 64 + mf * 16 + quad * 4) * N;
#pragma unroll
      for (int nf = 0; nf < 4; ++nf) {
        const int col = bn + bnr + nf * 16 + lq;
        if (OUTF32) {
          float* gp = (float*)Cout + rbase + col;
#pragma unroll
          for (int r = 0; r < 4; ++r) gp[(size_t)r * N] = acc[mh][mf][nf][r];
        } else {
          bf16* gp = (bf16*)Cout + rbase + col;
#pragma unroll
          for (int r = 0; r < 4; ++r) gp[(size_t)r * N] = (bf16)acc[mh][mf][nf][r];
        }
      }
    }
}

// ---------------------------------------------------------------------------
// RoPE in-place on qkv buffer (cols 0..5119 = q,k heads). One pair per thread.
__global__ __launch_bounds__(256) void rope_kernel(bf16* __restrict__ qkv,
                                                   const float* __restrict__ fc,
                                                   const float* __restrict__ fs) {
  const int p = blockIdx.x * 256 + threadIdx.x;  // 0..2559 pair index
  const int tok = blockIdx.y;                    // 0..4095
  const int s = tok & (SEQ - 1);
  const int dh = p & 63;
  const float c = fc[s * 64 + dh], sn = fs[s * 64 + dh];
  bf16* ptr = qkv + (size_t)tok * QKVN + 2 * p;
  bf16x2 v = *(bf16x2*)ptr;
  const float x0 = (float)v[0], x1 = (float)v[1];
  bf16x2 o;
  o[0] = (bf16)(x0 * c - x1 * sn);
  o[1] = (bf16)(x0 * sn + x1 * c);
  *(bf16x2*)ptr = o;
}

// ---------------------------------------------------------------------------
// V transpose: qkv V columns -> vt[(b*8+g)*HD + d][s]
__global__ __launch_bounds__(256) void tp_v(const bf16* __restrict__ qkv,
                                            bf16* __restrict__ vt) {
  __shared__ bf16 t[32][33];
  const int tx = threadIdx.x, ty = threadIdx.y;  // 32 x 8
  const int s0 = blockIdx.x * 32, d0 = blockIdx.y * 32, bg = blockIdx.z;
  const bf16* src = qkv + (size_t)((bg >> 3) * SEQ) * QKVN + VCOFF + (bg & 7) * HD;
#pragma unroll
  for (int yy = 0; yy < 32; yy += 8)
    t[ty + yy][tx] = src[(size_t)(s0 + ty + yy) * QKVN + d0 + tx];
  __syncthreads();
  bf16* dst = vt + (size_t)bg * HD * SEQ;
#pragma unroll
  for (int yy = 0; yy < 32; yy += 8)
    dst[(size_t)(d0 + ty + yy) * SEQ + s0 + tx] = t[tx][ty + yy];
}

// ---------------------------------------------------------------------------
// Flash attention (round-2 known-good): S^T formulation, in-loop DMA staging.
__global__ __launch_bounds__(256, 2) void attn_kernel(const bf16* __restrict__ qkv,
                                                      const bf16* __restrict__ vt,
                                                      bf16* __restrict__ aout) {
  __shared__ bf16 lK[128 * 128];  // 32KB: K tile, then P tile
  __shared__ bf16 lV[128 * 128];  // 32KB: V^T tile
  const int tid = threadIdx.x;
  const int w = tid >> 6, lane = tid & 63;
  const int quad = lane >> 4, lq = lane & 15;
  const int qt = (int)gridDim.x - 1 - (int)blockIdx.x;  // heavy blocks first
  const int h = blockIdx.y, b = blockIdx.z;
  const int g = h >> 2;  // kv head (N_REP = 4)
  const int qbase = qt * 128;
  const int wm = w * 32;  // wave's 32 q rows

  const float scale = 0.08838834764831845f;  // 1/sqrt(128)
  const bf16* qp = qkv + (size_t)(b * SEQ + qbase) * QKVN + h * HD;
  bf16x8 qf[2][4];
#pragma unroll
  for (int i2 = 0; i2 < 2; ++i2)
#pragma unroll
    for (int kk = 0; kk < 4; ++kk) {
      bf16x8 v = *(const bf16x8*)(qp + (size_t)(wm + i2 * 16 + lq) * QKVN + kk * 32 + quad * 8);
#pragma unroll
      for (int e = 0; e < 8; ++e) v[e] = (bf16)((float)v[e] * scale);
      qf[i2][kk] = v;
    }

  float mi[2] = {NEG_BIG, NEG_BIG}, li[2] = {0.f, 0.f};
  f32x4 oacc[8][2] = {};  // O^T[d = ds*16+quad*4+r][m = wm+i2*16+lq]

  const bf16* kb0 = qkv + (size_t)(b * SEQ) * QKVN + KCOFF + g * HD;
  const bf16* vt0 = vt + (size_t)(b * NKV + g) * HD * SEQ;

  for (int kt = 0; kt <= qt; ++kt) {
    // ---- stage K tile [n][d] and V^T tile [d][n], both chunk-swizzled ----
    const bf16* kb = kb0 + (size_t)(kt * 128) * QKVN;
#pragma unroll
    for (int i = 0; i < 8; ++i) {
      const int c = i * 256 + tid;        // physical 16B chunk 0..2047
      const int row = c >> 4;             // n for K, d for V^T
      const int lc = (c & 15) ^ (row & 15);
      GLL16(kb + (size_t)row * QKVN + lc * 8, lK + (i * 256 + w * 64) * 8);
      GLL16(vt0 + (size_t)row * SEQ + kt * 128 + lc * 8, lV + (i * 256 + w * 64) * 8);
    }
    __syncthreads();  // B1: tiles ready

    // ---- QK^T -> S^T: sacc[i2][ns], n = ns*16+quad*4+r, m = wm+i2*16+lq ----
    f32x4 sacc[2][8] = {};
#pragma unroll
    for (int kk = 0; kk < 4; ++kk) {
      bf16x8 kf[8];
#pragma unroll
      for (int ns = 0; ns < 8; ++ns) {
        const int n = ns * 16 + lq;
        kf[ns] = *(const bf16x8*)(lK + n * 128 + (((kk * 4 + quad) ^ (n & 15))) * 8);
      }
#pragma unroll
      for (int i2 = 0; i2 < 2; ++i2)
#pragma unroll
        for (int ns = 0; ns < 8; ++ns)
          sacc[i2][ns] = __builtin_amdgcn_mfma_f32_16x16x32_bf16(kf[ns], qf[i2][kk], sacc[i2][ns], 0, 0, 0);
    }
    __syncthreads();  // B2: lK reads done, safe to overwrite with P

    // ---- online softmax (per-lane state: column m = lq) ----
    const bool diag = (kt == qt);
#pragma unroll
    for (int i2 = 0; i2 < 2; ++i2) {
      const int m = wm + i2 * 16 + lq;
      if (diag) {
#pragma unroll
        for (int ns = 0; ns < 8; ++ns)
#pragma unroll
          for (int r = 0; r < 4; ++r)
            if (ns * 16 + quad * 4 + r > m) sacc[i2][ns][r] = NEG_BIG;
      }
      float mx = NEG_BIG;
#pragma unroll
      for (int ns = 0; ns < 8; ++ns)
#pragma unroll
        for (int r = 0; r < 4; ++r) mx = fmaxf(mx, sacc[i2][ns][r]);
      mx = fmaxf(mx, __shfl_xor(mx, 16));
      mx = fmaxf(mx, __shfl_xor(mx, 32));
      const float mnew = fmaxf(mi[i2], mx);
      const float al = __expf(mi[i2] - mnew);
      float rs = 0.f;
#pragma unroll
      for (int ns = 0; ns < 8; ++ns)
#pragma unroll
        for (int r = 0; r < 4; ++r) {
          const float e = __expf(sacc[i2][ns][r] - mnew);
          sacc[i2][ns][r] = e;
          rs += e;
        }
      rs += __shfl_xor(rs, 16);
      rs += __shfl_xor(rs, 32);
      li[i2] = li[i2] * al + rs;
      mi[i2] = mnew;
#pragma unroll
      for (int ds = 0; ds < 8; ++ds)
#pragma unroll
        for (int r = 0; r < 4; ++r) oacc[ds][i2][r] *= al;
    }

    // ---- write P [m][n] into lK (b64, swizzled) ----
#pragma unroll
    for (int i2 = 0; i2 < 2; ++i2) {
      const int m = wm + i2 * 16 + lq;
#pragma unroll
      for (int ns = 0; ns < 8; ++ns) {
        bf16x4 p4;
#pragma unroll
        for (int r = 0; r < 4; ++r) p4[r] = (bf16)sacc[i2][ns][r];
        const int n0 = ns * 16 + quad * 4;
        const int pc = (n0 >> 3) ^ (m & 15);
        *(bf16x4*)(lK + m * 128 + pc * 8 + (n0 & 7)) = p4;
      }
    }
    __syncthreads();  // B3: P visible

    // ---- PV: O^T[d][m] += MFMA(A = V^T, B = P) ----
#pragma unroll
    for (int gg = 0; gg < 4; ++gg) {
      bf16x8 pf[2];
#pragma unroll
      for (int i2 = 0; i2 < 2; ++i2) {
        const int m = wm + i2 * 16 + lq;
        pf[i2] = *(const bf16x8*)(lK + m * 128 + (((gg * 4 + quad) ^ (m & 15))) * 8);
      }
#pragma unroll
      for (int ds = 0; ds < 8; ++ds) {
        const int d = ds * 16 + lq;
        bf16x8 vf = *(const bf16x8*)(lV + d * 128 + (((gg * 4 + quad) ^ (d & 15))) * 8);
#pragma unroll
        for (int i2 = 0; i2 < 2; ++i2)
          oacc[ds][i2] = __builtin_amdgcn_mfma_f32_16x16x32_bf16(vf, pf[i2], oacc[ds][i2], 0, 0, 0);
      }
    }
    __syncthreads();  // B4: lK/lV reads done before next staging
  }

  // ---- epilogue: O^T/l -> LDS [m][d] (swizzled) -> coalesced global ----
#pragma unroll
  for (int ds = 0; ds < 8; ++ds)
#pragma unroll
    for (int i2 = 0; i2 < 2; ++i2) {
      const int m = wm + i2 * 16 + lq;
      const float inv = 1.0f / li[i2];
      bf16x4 o4;
#pragma unroll
      for (int r = 0; r < 4; ++r) o4[r] = (bf16)(oacc[ds][i2][r] * inv);
      const int d0 = ds * 16 + quad * 4;
      const int pc = (d0 >> 3) ^ (m & 15);
      *(bf16x4*)(lK + m * 128 + pc * 8 + (d0 & 7)) = o4;
    }
  __syncthreads();
  {
    const int m = tid >> 1, hf = tid & 1;
    bf16* ob = aout + (size_t)(b * SEQ + qbase + m) * (NH * HD) + h * HD + hf * 64;
#pragma unroll
    for (int c = 0; c < 8; ++c) {
      const int lc = hf * 8 + c;
      bf16x8 vv = *(const bf16x8*)(lK + m * 128 + ((lc ^ (m & 15))) * 8);
      *(bf16x8*)(ob + c * 8) = vv;
    }
  }
}

// ---------------------------------------------------------------------------
extern "C" void kernel_launch(void* const* d_in, const int* in_sizes, int n_in,
                              void* d_out, int out_size, void* d_ws, size_t ws_size,
                              hipStream_t stream) {
  (void)in_sizes; (void)n_in; (void)out_size; (void)ws_size;
  const float* x  = (const float*)d_in[0];
  const float* fc = (const float*)d_in[2];
  const float* fs = (const float*)d_in[3];
  const float* wq = (const float*)d_in[6];
  const float* wk = (const float*)d_in[7];
  const float* wv = (const float*)d_in[8];
  const float* wo = (const float*)d_in[9];

  char* ws = (char*)d_ws;
  // layout: [0,48MB) wT (wqkv^T; later wo^T in [0,32MB) + vt in [32,40MB))
  //         [48,80MB) xb (later attn out) | [80,128MB) qkv
  bf16* wT   = (bf16*)ws;
  bf16* vtb  = (bf16*)(ws + 33554432);
  bf16* xb   = (bf16*)(ws + 50331648);
  bf16* qkvb = (bf16*)(ws + 83886080);
  float* outp = (float*)d_out;

  const dim3 tb(32, 8);
  transpose_cvt3<<<dim3(QKVN / 32, DIM / 32), tb, 0, stream>>>(wq, wk, wv, wT);
  cvt_f32_bf16<<<(NTOK * DIM) / 1024, 256, 0, stream>>>(x, xb);
  gemm256<false><<<dim3((QKVN / 256) * (NTOK / 256)), 512, 0, stream>>>(xb, wT, qkvb, NTOK, QKVN, DIM);
  rope_kernel<<<dim3(10, NTOK), 256, 0, stream>>>(qkvb, fc, fs);
  tp_v<<<dim3(SEQ / 32, HD / 32, BATCH * NKV), tb, 0, stream>>>(qkvb, vtb);
  transpose_cvt<<<dim3(DIM / 32, (NH * HD) / 32), tb, 0, stream>>>(wo, wT, NH * HD, DIM);
  attn_kernel<<<dim3(SEQ / 128, NH, BATCH), 256, 0, stream>>>(qkvb, vtb, xb);
  gemm256<true><<<dim3((DIM / 256) * (NTOK / 256)), 512, 0, stream>>>(xb, wT, outp, NTOK, DIM, NH * HD);
}

// Round 4
// 816.879 us; speedup vs baseline: 1.1266x; 1.0665x over previous
//
#include <hip/hip_runtime.h>
#include <cstdint>

typedef __bf16 bf16;
typedef __bf16 bf16x2 __attribute__((ext_vector_type(2)));
typedef __bf16 bf16x4 __attribute__((ext_vector_type(4)));
typedef __bf16 bf16x8 __attribute__((ext_vector_type(8)));
typedef float  f32x4  __attribute__((ext_vector_type(4)));

#define DIM   4096
#define NH    32
#define NKV   8
#define HD    128
#define BATCH 2
#define SEQ   2048
#define NTOK  (BATCH * SEQ)   // 4096
#define QKVN  6144            // NH*HD + 2*NKV*HD
#define KCOFF 4096            // k column offset in qkv buffer
#define VCOFF 5120            // v column offset
#define NEG_BIG (-1e30f)

// async global->LDS, 16B per lane; LDS dest is wave-uniform base + lane*16
#define GLL16(gp, lp)                                                          \
  __builtin_amdgcn_global_load_lds(                                            \
      (__attribute__((address_space(1))) uint32_t*)(gp),                       \
      (__attribute__((address_space(3))) uint32_t*)(lp), 16, 0, 0)

// ---------------------------------------------------------------------------
// fused wq/wk/wv transpose+convert into concatenated wT[6144][4096]
__global__ __launch_bounds__(256) void transpose_cvt3(const float* __restrict__ wq,
                                                      const float* __restrict__ wk,
                                                      const float* __restrict__ wv,
                                                      bf16* __restrict__ out) {
  __shared__ float t[32][33];
  const int tx = threadIdx.x, ty = threadIdx.y;
  const int n0 = blockIdx.x * 32;  // col in concat [0,6144)
  const int k0 = blockIdx.y * 32;  // row (K dim)
  const float* src; int c0, C;
  if (n0 < 4096)      { src = wq; c0 = n0;        C = 4096; }
  else if (n0 < 5120) { src = wk; c0 = n0 - 4096; C = 1024; }
  else                { src = wv; c0 = n0 - 5120; C = 1024; }
#pragma unroll
  for (int yy = 0; yy < 32; yy += 8)
    t[ty + yy][tx] = src[(size_t)(k0 + ty + yy) * C + c0 + tx];
  __syncthreads();
#pragma unroll
  for (int yy = 0; yy < 32; yy += 8)
    out[(size_t)(n0 + ty + yy) * DIM + k0 + tx] = (bf16)t[tx][ty + yy];
}

// transpose + convert: in[R][C] f32 -> out[C][R] bf16 (for wo)
__global__ __launch_bounds__(256) void transpose_cvt(const float* __restrict__ in,
                                                     bf16* __restrict__ out,
                                                     int R, int C) {
  __shared__ float t[32][33];
  const int tx = threadIdx.x, ty = threadIdx.y;
  const int gx = blockIdx.x * 32, gy = blockIdx.y * 32;
#pragma unroll
  for (int yy = 0; yy < 32; yy += 8)
    t[ty + yy][tx] = in[(size_t)(gy + ty + yy) * C + gx + tx];
  __syncthreads();
#pragma unroll
  for (int yy = 0; yy < 32; yy += 8)
    out[(size_t)(gx + ty + yy) * R + gy + tx] = (bf16)t[tx][ty + yy];
}

// elementwise fp32 -> bf16, 4 per thread
__global__ __launch_bounds__(256) void cvt_f32_bf16(const float* __restrict__ in,
                                                    bf16* __restrict__ out) {
  size_t i = ((size_t)blockIdx.x * 256 + threadIdx.x) * 4;
  f32x4 v = *(const f32x4*)(in + i);
  bf16x4 o;
  o[0] = (bf16)v[0]; o[1] = (bf16)v[1]; o[2] = (bf16)v[2]; o[3] = (bf16)v[3];
  *(bf16x4*)(out + i) = o;
}

// ---------------------------------------------------------------------------
// 256x256 8-wave GEMM, BK=64, 4 phases/K-tile, counted vmcnt (never 0 in
// steady state), XOR-swizzled LDS (conflict-free ds_read_b128), setprio
// around MFMA clusters. C[M][N] = A[M][K] @ BT[N][K]^T.
#define STG(bufsel, ab, kh, tile, gp)                                          \
  do {                                                                         \
    bf16* lh_ = lds + (((bufsel) * 4 + (ab) * 2 + (kh)) * 8192);               \
    const bf16* gr_ = (gp) + (size_t)(tile) * 64 + (kh) * 32 + sgc * 8;        \
    GLL16(gr_ + (size_t)sr0 * K, lh_ + (w << 6) * 8);                          \
    GLL16(gr_ + (size_t)sr1 * K, lh_ + (512 + (w << 6)) * 8);                  \
  } while (0)

#define FRAG(bufsel, ab, kh, row)                                              \
  (*(const bf16x8*)(lds + (((bufsel) * 4 + (ab) * 2 + (kh)) * 8192) +          \
                    (row) * 32 + ((quad ^ (((row) >> 1) & 3)) << 3)))

#define MFMA_CLUSTER(mh, AFR)                                                  \
  do {                                                                         \
    __builtin_amdgcn_s_setprio(1);                                             \
    _Pragma("unroll")                                                          \
    for (int mf = 0; mf < 4; ++mf)                                             \
      _Pragma("unroll")                                                        \
      for (int nf = 0; nf < 4; ++nf)                                           \
        acc[mh][mf][nf] = __builtin_amdgcn_mfma_f32_16x16x32_bf16(             \
            AFR[mf], bF[nf], acc[mh][mf][nf], 0, 0, 0);                        \
    __builtin_amdgcn_s_setprio(0);                                             \
  } while (0)

template <bool OUTF32>
__global__ __launch_bounds__(512, 2) void gemm256(const bf16* __restrict__ A,
                                                  const bf16* __restrict__ BT,
                                                  void* __restrict__ Cout,
                                                  int M, int N, int K) {
  __shared__ __align__(16) bf16 lds[65536];  // 128 KiB
  const int tid = threadIdx.x;
  const int w = tid >> 6, lane = tid & 63;
  const int quad = lane >> 4, lq = lane & 15;
  const int wmi = w >> 2, wni = w & 3;  // 2 (M) x 4 (N) waves

  // bijective XCD swizzle on flat 1-D grid (nwg % 8 == 0 here: 384, 256)
  const int nbx = N >> 8;
  const int nwg = (int)gridDim.x;
  const int flat = (int)blockIdx.x;
  const int swz = (flat & 7) * (nwg >> 3) + (flat >> 3);
  const int bm = (swz / nbx) << 8, bn = (swz % nbx) << 8;

  const bf16* aB = A + (size_t)bm * K;
  const bf16* bB = BT + (size_t)bn * K;
  const int NT = K >> 6;

  // staging geometry (chunk c = l*512 + tid; row = c>>2; swizzled chunk pos)
  const int sgc = (tid & 3) ^ ((tid >> 3) & 3);
  const int sr0 = tid >> 2, sr1 = sr0 + 128;
  const int am = wmi * 128, bnr = wni * 64;

  f32x4 acc[2][4][4] = {};

  // ---- prologue: tile0 complete + {Ak0,Bk0}(1) in flight ----
  STG(0, 0, 0, 0, aB); STG(0, 1, 0, 0, bB);
  STG(0, 0, 1, 0, aB); STG(0, 1, 1, 0, bB);
  STG(1, 0, 0, 1, aB); STG(1, 1, 0, 1, bB);
  asm volatile("s_waitcnt vmcnt(4)" ::: "memory");
  __builtin_amdgcn_s_barrier();

  for (int t = 0; t < NT; ++t) {
    const int cb = t & 1, ob = cb ^ 1;
    bf16x8 aF[4], bF[4], a2[4];

    // ---- phase 1: (m0, k0) ----
#pragma unroll
    for (int f = 0; f < 4; ++f) aF[f] = FRAG(cb, 0, 0, am + f * 16 + lq);
#pragma unroll
    for (int f = 0; f < 4; ++f) bF[f] = FRAG(cb, 1, 0, bnr + f * 16 + lq);
    if (t + 1 < NT) STG(ob, 0, 1, t + 1, aB);
    __builtin_amdgcn_s_barrier();
    asm volatile("s_waitcnt lgkmcnt(0)" ::: "memory");
    MFMA_CLUSTER(0, aF);
    __builtin_amdgcn_s_barrier();

    // ---- phase 2: (m1, k0) ----
#pragma unroll
    for (int f = 0; f < 4; ++f) a2[f] = FRAG(cb, 0, 0, am + 64 + f * 16 + lq);
    if (t + 1 < NT) STG(ob, 1, 1, t + 1, bB);
    __builtin_amdgcn_s_barrier();
    asm volatile("s_waitcnt lgkmcnt(0)" ::: "memory");
    MFMA_CLUSTER(1, a2);
    __builtin_amdgcn_s_barrier();

    // ---- phase 3: (m0, k1) ----
    if (t == NT - 1) asm volatile("s_waitcnt vmcnt(0)" ::: "memory");
#pragma unroll
    for (int f = 0; f < 4; ++f) aF[f] = FRAG(cb, 0, 1, am + f * 16 + lq);
#pragma unroll
    for (int f = 0; f < 4; ++f) bF[f] = FRAG(cb, 1, 1, bnr + f * 16 + lq);
    if (t + 2 < NT) STG(cb, 0, 0, t + 2, aB);
    __builtin_amdgcn_s_barrier();
    asm volatile("s_waitcnt lgkmcnt(0)" ::: "memory");
    MFMA_CLUSTER(0, aF);
    __builtin_amdgcn_s_barrier();

    // ---- phase 4: (m1, k1) ----
#pragma unroll
    for (int f = 0; f < 4; ++f) a2[f] = FRAG(cb, 0, 1, am + 64 + f * 16 + lq);
    if (t + 2 < NT) STG(cb, 1, 0, t + 2, bB);
    asm volatile("s_waitcnt vmcnt(4)" ::: "memory");
    __builtin_amdgcn_s_barrier();
    asm volatile("s_waitcnt lgkmcnt(0)" ::: "memory");
    MFMA_CLUSTER(1, a2);
    __builtin_amdgcn_s_barrier();
  }

  // ---- epilogue: direct stores (16-lane contiguous segments per quad) ----
#pragma unroll
  for (int mh = 0; mh < 2; ++mh)
#pragma unroll
    for (int mf = 0; mf < 4; ++mf) {
      const size_t rbase =
          (size_t)(bm + am + mh * 64 + mf * 16 + quad * 4) * N;
#pragma unroll
      for (int nf = 0; nf < 4; ++nf) {
        const int col = bn + bnr + nf * 16 + lq;
        if (OUTF32) {
          float* gp = (float*)Cout + rbase + col;
#pragma unroll
          for (int r = 0; r < 4; ++r) gp[(size_t)r * N] = acc[mh][mf][nf][r];
        } else {
          bf16* gp = (bf16*)Cout + rbase + col;
#pragma unroll
          for (int r = 0; r < 4; ++r) gp[(size_t)r * N] = (bf16)acc[mh][mf][nf][r];
        }
      }
    }
}

// ---------------------------------------------------------------------------
// RoPE in-place on qkv buffer (cols 0..5119 = q,k heads). One pair per thread.
__global__ __launch_bounds__(256) void rope_kernel(bf16* __restrict__ qkv,
                                                   const float* __restrict__ fc,
                                                   const float* __restrict__ fs) {
  const int p = blockIdx.x * 256 + threadIdx.x;  // 0..2559 pair index
  const int tok = blockIdx.y;                    // 0..4095
  const int s = tok & (SEQ - 1);
  const int dh = p & 63;
  const float c = fc[s * 64 + dh], sn = fs[s * 64 + dh];
  bf16* ptr = qkv + (size_t)tok * QKVN + 2 * p;
  bf16x2 v = *(bf16x2*)ptr;
  const float x0 = (float)v[0], x1 = (float)v[1];
  bf16x2 o;
  o[0] = (bf16)(x0 * c - x1 * sn);
  o[1] = (bf16)(x0 * sn + x1 * c);
  *(bf16x2*)ptr = o;
}

// ---------------------------------------------------------------------------
// V transpose: qkv V columns -> vt[(b*8+g)*HD + d][s]
__global__ __launch_bounds__(256) void tp_v(const bf16* __restrict__ qkv,
                                            bf16* __restrict__ vt) {
  __shared__ bf16 t[32][33];
  const int tx = threadIdx.x, ty = threadIdx.y;  // 32 x 8
  const int s0 = blockIdx.x * 32, d0 = blockIdx.y * 32, bg = blockIdx.z;
  const bf16* src = qkv + (size_t)((bg >> 3) * SEQ) * QKVN + VCOFF + (bg & 7) * HD;
#pragma unroll
  for (int yy = 0; yy < 32; yy += 8)
    t[ty + yy][tx] = src[(size_t)(s0 + ty + yy) * QKVN + d0 + tx];
  __syncthreads();
  bf16* dst = vt + (size_t)bg * HD * SEQ;
#pragma unroll
  for (int yy = 0; yy < 32; yy += 8)
    dst[(size_t)(d0 + ty + yy) * SEQ + s0 + tx] = t[tx][ty + yy];
}

// ---------------------------------------------------------------------------
// Flash attention: S^T formulation, KVBLK=64, double-buffered K/V staging with
// counted vmcnt (tile t+1 loads stay in flight across all barriers of tile t).
// Raw s_barrier + manual lgkmcnt fences (no __syncthreads in-loop: its
// vmcnt(0) drain would kill the pipeline).
// LDS: lK[2][64x128] (K tile; P tile reuses current buf), lV[2][128x64] (V^T).
// Staging swizzle (both-sides XOR): K row=0..63, 16 chunks: LDS[r][p] holds
// global chunk p^(r&15); V^T row=0..127, 8 chunks: p^(r&7); P write/read
// uses ^(m&7) over 8 chunks.
#define ASTAGE(tt, bufsel)                                                     \
  do {                                                                         \
    const bf16* kb_ = kb0 + (size_t)((tt) * 64) * QKVN;                        \
    const bf16* vb_ = vt0 + (size_t)((tt) * 64);                               \
    _Pragma("unroll")                                                          \
    for (int i_ = 0; i_ < 4; ++i_) {                                           \
      const int c_ = i_ * 256 + tid;                                           \
      const int kr_ = c_ >> 4, kc_ = (c_ & 15) ^ (kr_ & 15);                   \
      GLL16(kb_ + (size_t)kr_ * QKVN + kc_ * 8,                                \
            lK + (bufsel) * 8192 + (i_ * 256 + w * 64) * 8);                   \
      const int vr_ = c_ >> 3, vc_ = (c_ & 7) ^ (vr_ & 7);                     \
      GLL16(vb_ + (size_t)vr_ * SEQ + vc_ * 8,                                 \
            lV + (bufsel) * 8192 + (i_ * 256 + w * 64) * 8);                   \
    }                                                                          \
  } while (0)

__global__ __launch_bounds__(256, 2) void attn_kernel(const bf16* __restrict__ qkv,
                                                      const bf16* __restrict__ vt,
                                                      bf16* __restrict__ aout) {
  __shared__ bf16 lK[2 * 64 * 128];  // 32KB: K tiles (double-buf); P in cur buf
  __shared__ bf16 lV[2 * 64 * 128];  // 32KB: V^T tiles (double-buf)
  const int tid = threadIdx.x;
  const int w = tid >> 6, lane = tid & 63;
  const int quad = lane >> 4, lq = lane & 15;
  const int qt = (int)gridDim.x - 1 - (int)blockIdx.x;  // heavy blocks first
  const int h = blockIdx.y, b = blockIdx.z;
  const int g = h >> 2;  // kv head (N_REP = 4)
  const int qbase = qt * 128;
  const int wm = w * 32;  // wave's 32 q rows

  const float scale = 0.08838834764831845f;  // 1/sqrt(128)
  const bf16* qp = qkv + (size_t)(b * SEQ + qbase) * QKVN + h * HD;
  bf16x8 qf[2][4];
#pragma unroll
  for (int i2 = 0; i2 < 2; ++i2)
#pragma unroll
    for (int kk = 0; kk < 4; ++kk) {
      bf16x8 v = *(const bf16x8*)(qp + (size_t)(wm + i2 * 16 + lq) * QKVN + kk * 32 + quad * 8);
#pragma unroll
      for (int e = 0; e < 8; ++e) v[e] = (bf16)((float)v[e] * scale);
      qf[i2][kk] = v;
    }

  float mi[2] = {NEG_BIG, NEG_BIG}, li[2] = {0.f, 0.f};
  f32x4 oacc[8][2] = {};  // O^T[d = ds*16+quad*4+r][m = wm+i2*16+lq]

  const bf16* kb0 = qkv + (size_t)(b * SEQ) * QKVN + KCOFF + g * HD;
  const bf16* vt0 = vt + (size_t)(b * NKV + g) * HD * SEQ;

  const int nt = 2 * qt + 2;  // number of 64-row KV tiles

  // prologue: stage tile 0 into buf 0
  ASTAGE(0, 0);

  for (int kt = 0; kt < nt; ++kt) {
    const int cb = kt & 1, ob = cb ^ 1;
    bf16* lKc = lK + cb * 8192;
    bf16* lVc = lV + cb * 8192;

    // issue next tile's staging, then wait only for tile kt's 8 loads
    if (kt + 1 < nt) {
      ASTAGE(kt + 1, ob);
      asm volatile("s_waitcnt vmcnt(8)" ::: "memory");
    } else {
      asm volatile("s_waitcnt vmcnt(0)" ::: "memory");
    }
    __builtin_amdgcn_s_barrier();  // B1: tile kt ready in buf cb

    // ---- QK^T -> S^T: sacc[i2][ns], n = ns*16+quad*4+r (tile-local) ----
    f32x4 sacc[2][4] = {};
#pragma unroll
    for (int kk = 0; kk < 4; ++kk) {
      bf16x8 kf[4];
#pragma unroll
      for (int ns = 0; ns < 4; ++ns) {
        const int n = ns * 16 + lq;
        kf[ns] = *(const bf16x8*)(lKc + n * 128 + (((kk * 4 + quad) ^ (n & 15))) * 8);
      }
#pragma unroll
      for (int i2 = 0; i2 < 2; ++i2)
#pragma unroll
        for (int ns = 0; ns < 4; ++ns)
          sacc[i2][ns] = __builtin_amdgcn_mfma_f32_16x16x32_bf16(kf[ns], qf[i2][kk], sacc[i2][ns], 0, 0, 0);
    }
    asm volatile("s_waitcnt lgkmcnt(0)" ::: "memory");
    __builtin_amdgcn_s_barrier();  // B2: lK[cb] reads done -> safe for P

    // ---- online softmax (per-lane state: column m = lq) ----
    const int rel = (kt - 2 * qt) * 64;  // tile n-offset minus qbase
#pragma unroll
    for (int i2 = 0; i2 < 2; ++i2) {
      const int m = wm + i2 * 16 + lq;
      if (rel > -64) {  // only last two tiles can touch the diagonal
#pragma unroll
        for (int ns = 0; ns < 4; ++ns)
#pragma unroll
          for (int r = 0; r < 4; ++r)
            if (rel + ns * 16 + quad * 4 + r > m) sacc[i2][ns][r] = NEG_BIG;
      }
      float mx = NEG_BIG;
#pragma unroll
      for (int ns = 0; ns < 4; ++ns)
#pragma unroll
        for (int r = 0; r < 4; ++r) mx = fmaxf(mx, sacc[i2][ns][r]);
      mx = fmaxf(mx, __shfl_xor(mx, 16));
      mx = fmaxf(mx, __shfl_xor(mx, 32));
      const float mnew = fmaxf(mi[i2], mx);
      const float al = __expf(mi[i2] - mnew);
      float rs = 0.f;
#pragma unroll
      for (int ns = 0; ns < 4; ++ns)
#pragma unroll
        for (int r = 0; r < 4; ++r) {
          const float e = __expf(sacc[i2][ns][r] - mnew);
          sacc[i2][ns][r] = e;
          rs += e;
        }
      rs += __shfl_xor(rs, 16);
      rs += __shfl_xor(rs, 32);
      li[i2] = li[i2] * al + rs;
      mi[i2] = mnew;
#pragma unroll
      for (int ds = 0; ds < 8; ++ds)
#pragma unroll
        for (int r = 0; r < 4; ++r) oacc[ds][i2][r] *= al;
    }

    // ---- write P [m][n] into lK[cb] (row stride 64, ^(m&7) chunk swizzle) --
#pragma unroll
    for (int i2 = 0; i2 < 2; ++i2) {
      const int m = wm + i2 * 16 + lq;
#pragma unroll
      for (int ns = 0; ns < 4; ++ns) {
        bf16x4 p4;
#pragma unroll
        for (int r = 0; r < 4; ++r) p4[r] = (bf16)sacc[i2][ns][r];
        const int n0 = ns * 16 + quad * 4;
        const int pc = (n0 >> 3) ^ (m & 7);
        *(bf16x4*)(lKc + m * 64 + pc * 8 + (n0 & 7)) = p4;
      }
    }
    asm volatile("s_waitcnt lgkmcnt(0)" ::: "memory");
    __builtin_amdgcn_s_barrier();  // B3: P visible

    // ---- PV: O^T[d][m] += MFMA(A = V^T, B = P), contraction = 64 ----
#pragma unroll
    for (int gg = 0; gg < 2; ++gg) {
      bf16x8 pf[2];
#pragma unroll
      for (int i2 = 0; i2 < 2; ++i2) {
        const int m = wm + i2 * 16 + lq;
        pf[i2] = *(const bf16x8*)(lKc + m * 64 + (((gg * 4 + quad) ^ (m & 7))) * 8);
      }
#pragma unroll
      for (int ds = 0; ds < 8; ++ds) {
        const int d = ds * 16 + lq;
        bf16x8 vf = *(const bf16x8*)(lVc + d * 64 + (((gg * 4 + quad) ^ (d & 7))) * 8);
#pragma unroll
        for (int i2 = 0; i2 < 2; ++i2)
          oacc[ds][i2] = __builtin_amdgcn_mfma_f32_16x16x32_bf16(vf, pf[i2], oacc[ds][i2], 0, 0, 0);
      }
    }
    asm volatile("s_waitcnt lgkmcnt(0)" ::: "memory");
    __builtin_amdgcn_s_barrier();  // B4: buf cb reads done before re-stage
  }

  // ---- epilogue: O^T/l -> LDS [m][128] (32KB = both lK bufs) -> global ----
#pragma unroll
  for (int ds = 0; ds < 8; ++ds)
#pragma unroll
    for (int i2 = 0; i2 < 2; ++i2) {
      const int m = wm + i2 * 16 + lq;
      const float inv = 1.0f / li[i2];
      bf16x4 o4;
#pragma unroll
      for (int r = 0; r < 4; ++r) o4[r] = (bf16)(oacc[ds][i2][r] * inv);
      const int d0 = ds * 16 + quad * 4;
      const int pc = (d0 >> 3) ^ (m & 15);
      *(bf16x4*)(lK + m * 128 + pc * 8 + (d0 & 7)) = o4;
    }
  __syncthreads();
  {
    const int m = tid >> 1, hf = tid & 1;
    bf16* ob = aout + (size_t)(b * SEQ + qbase + m) * (NH * HD) + h * HD + hf * 64;
#pragma unroll
    for (int c = 0; c < 8; ++c) {
      const int lc = hf * 8 + c;
      bf16x8 vv = *(const bf16x8*)(lK + m * 128 + ((lc ^ (m & 15))) * 8);
      *(bf16x8*)(ob + c * 8) = vv;
    }
  }
}

// ---------------------------------------------------------------------------
extern "C" void kernel_launch(void* const* d_in, const int* in_sizes, int n_in,
                              void* d_out, int out_size, void* d_ws, size_t ws_size,
                              hipStream_t stream) {
  (void)in_sizes; (void)n_in; (void)out_size; (void)ws_size;
  const float* x  = (const float*)d_in[0];
  const float* fc = (const float*)d_in[2];
  const float* fs = (const float*)d_in[3];
  const float* wq = (const float*)d_in[6];
  const float* wk = (const float*)d_in[7];
  const float* wv = (const float*)d_in[8];
  const float* wo = (const float*)d_in[9];

  char* ws = (char*)d_ws;
  // layout: [0,48MB) wT (wqkv^T; later wo^T in [0,32MB) + vt in [32,40MB))
  //         [48,80MB) xb (later attn out) | [80,128MB) qkv
  bf16* wT   = (bf16*)ws;
  bf16* vtb  = (bf16*)(ws + 33554432);
  bf16* xb   = (bf16*)(ws + 50331648);
  bf16* qkvb = (bf16*)(ws + 83886080);
  float* outp = (float*)d_out;

  const dim3 tb(32, 8);
  transpose_cvt3<<<dim3(QKVN / 32, DIM / 32), tb, 0, stream>>>(wq, wk, wv, wT);
  cvt_f32_bf16<<<(NTOK * DIM) / 1024, 256, 0, stream>>>(x, xb);
  gemm256<false><<<dim3((QKVN / 256) * (NTOK / 256)), 512, 0, stream>>>(xb, wT, qkvb, NTOK, QKVN, DIM);
  rope_kernel<<<dim3(10, NTOK), 256, 0, stream>>>(qkvb, fc, fs);
  tp_v<<<dim3(SEQ / 32, HD / 32, BATCH * NKV), tb, 0, stream>>>(qkvb, vtb);
  transpose_cvt<<<dim3(DIM / 32, (NH * HD) / 32), tb, 0, stream>>>(wo, wT, NH * HD, DIM);
  attn_kernel<<<dim3(SEQ / 128, NH, BATCH), 256, 0, stream>>>(qkvb, vtb, xb);
  gemm256<true><<<dim3((DIM / 256) * (NTOK / 256)), 512, 0, stream>>>(xb, wT, outp, NTOK, DIM, NH * HD);
}

// Round 5
// 815.849 us; speedup vs baseline: 1.1280x; 1.0013x over previous
//
#include <hip/hip_runtime.h>
#include <cstdint>

typedef __bf16 bf16;
typedef __bf16 bf16x2 __attribute__((ext_vector_type(2)));
typedef __bf16 bf16x4 __attribute__((ext_vector_type(4)));
typedef __bf16 bf16x8 __attribute__((ext_vector_type(8)));
typedef float  f32x4  __attribute__((ext_vector_type(4)));

#define DIM   4096
#define NH    32
#define NKV   8
#define HD    128
#define BATCH 2
#define SEQ   2048
#define NTOK  (BATCH * SEQ)   // 4096
#define QKVN  6144            // NH*HD + 2*NKV*HD
#define KCOFF 4096            // k column offset in qkv buffer
#define VCOFF 5120            // v column offset
#define NEG_BIG (-1e30f)

// async global->LDS, 16B per lane; LDS dest is wave-uniform base + lane*16
#define GLL16(gp, lp)                                                          \
  __builtin_amdgcn_global_load_lds(                                            \
      (__attribute__((address_space(1))) uint32_t*)(gp),                       \
      (__attribute__((address_space(3))) uint32_t*)(lp), 16, 0, 0)

// ---------------------------------------------------------------------------
// fused wq/wk/wv transpose+convert into concatenated wT[6144][4096]
__global__ __launch_bounds__(256) void transpose_cvt3(const float* __restrict__ wq,
                                                      const float* __restrict__ wk,
                                                      const float* __restrict__ wv,
                                                      bf16* __restrict__ out) {
  __shared__ float t[32][33];
  const int tx = threadIdx.x, ty = threadIdx.y;
  const int n0 = blockIdx.x * 32;  // col in concat [0,6144)
  const int k0 = blockIdx.y * 32;  // row (K dim)
  const float* src; int c0, C;
  if (n0 < 4096)      { src = wq; c0 = n0;        C = 4096; }
  else if (n0 < 5120) { src = wk; c0 = n0 - 4096; C = 1024; }
  else                { src = wv; c0 = n0 - 5120; C = 1024; }
#pragma unroll
  for (int yy = 0; yy < 32; yy += 8)
    t[ty + yy][tx] = src[(size_t)(k0 + ty + yy) * C + c0 + tx];
  __syncthreads();
#pragma unroll
  for (int yy = 0; yy < 32; yy += 8)
    out[(size_t)(n0 + ty + yy) * DIM + k0 + tx] = (bf16)t[tx][ty + yy];
}

// transpose + convert: in[R][C] f32 -> out[C][R] bf16 (for wo)
__global__ __launch_bounds__(256) void transpose_cvt(const float* __restrict__ in,
                                                     bf16* __restrict__ out,
                                                     int R, int C) {
  __shared__ float t[32][33];
  const int tx = threadIdx.x, ty = threadIdx.y;
  const int gx = blockIdx.x * 32, gy = blockIdx.y * 32;
#pragma unroll
  for (int yy = 0; yy < 32; yy += 8)
    t[ty + yy][tx] = in[(size_t)(gy + ty + yy) * C + gx + tx];
  __syncthreads();
#pragma unroll
  for (int yy = 0; yy < 32; yy += 8)
    out[(size_t)(gx + ty + yy) * R + gy + tx] = (bf16)t[tx][ty + yy];
}

// elementwise fp32 -> bf16, 4 per thread
__global__ __launch_bounds__(256) void cvt_f32_bf16(const float* __restrict__ in,
                                                    bf16* __restrict__ out) {
  size_t i = ((size_t)blockIdx.x * 256 + threadIdx.x) * 4;
  f32x4 v = *(const f32x4*)(in + i);
  bf16x4 o;
  o[0] = (bf16)v[0]; o[1] = (bf16)v[1]; o[2] = (bf16)v[2]; o[3] = (bf16)v[3];
  *(bf16x4*)(out + i) = o;
}

// ---------------------------------------------------------------------------
// 256x256 8-wave GEMM, BK=32, TRIPLE-buffered LDS (96KB), 2 phases/K-tile,
// counted vmcnt(4) once per tile => ~3.5-phase prefetch lookahead (covers
// L2/LLC latency; the old 2-buffer BK=64 schedule only had ~2 phases).
// XOR-swizzled LDS (0 bank conflicts measured), setprio around MFMA clusters.
// C[M][N] = A[M][K] @ BT[N][K]^T.
//
// LDS: [buf(3)][A(256x32) | B(256x32)] = 3 x 32KB = 96KB.
// Swizzle: LDS[row][p] (16B chunks p=0..3) holds global chunk p^((row>>1)&3).
// Staging: tile = 256x32 per operand = 1024 chunks; thread stages chunks tid
// and 512+tid (same swizzle for both: rows differ by 128 == 0 mod 4).
//
// Per K-tile t (buf cb = t%3, prefetch buf pb = (t+2)%3 = tile t-1's buffer,
// whose reads retired before tile t-1's last lgkmcnt(0)+barrier):
//  P1: read A(m0)x4 + B x4 ; stage A(t+2)->pb ; bar; lgkm0; 16 MFMA; bar
//  P2: read A(m1)x4        ; stage B(t+2)->pb ; vmcnt(4); bar; lgkm0; 16 MFMA; bar
// vmcnt(4) at P2 retires tile t+1's 4 loads (issued back in tile t-1) while
// leaving tile t+2's 4 in flight. Tail (t+2 >= NT): vmcnt(0) drains.
#define STG_A(bufsel, tile)                                                    \
  do {                                                                         \
    bf16* lh_ = lds + (bufsel) * 16384;                                        \
    const bf16* gr_ = aB + (size_t)(tile) * 32 + sgc * 8;                      \
    GLL16(gr_ + (size_t)sr0 * K, lh_ + (w << 6) * 8);                          \
    GLL16(gr_ + (size_t)sr1 * K, lh_ + (512 + (w << 6)) * 8);                  \
  } while (0)

#define STG_B(bufsel, tile)                                                    \
  do {                                                                         \
    bf16* lh_ = lds + (bufsel) * 16384 + 8192;                                 \
    const bf16* gr_ = bB + (size_t)(tile) * 32 + sgc * 8;                      \
    GLL16(gr_ + (size_t)sr0 * K, lh_ + (w << 6) * 8);                          \
    GLL16(gr_ + (size_t)sr1 * K, lh_ + (512 + (w << 6)) * 8);                  \
  } while (0)

#define FRAG_A(bufsel, row)                                                    \
  (*(const bf16x8*)(lds + (bufsel) * 16384 + (row) * 32 +                      \
                    ((quad ^ (((row) >> 1) & 3)) << 3)))
#define FRAG_B(bufsel, row)                                                    \
  (*(const bf16x8*)(lds + (bufsel) * 16384 + 8192 + (row) * 32 +               \
                    ((quad ^ (((row) >> 1) & 3)) << 3)))

#define MFMA_CLUSTER(mh, AFR)                                                  \
  do {                                                                         \
    __builtin_amdgcn_s_setprio(1);                                             \
    _Pragma("unroll")                                                          \
    for (int mf = 0; mf < 4; ++mf)                                             \
      _Pragma("unroll")                                                        \
      for (int nf = 0; nf < 4; ++nf)                                           \
        acc[mh][mf][nf] = __builtin_amdgcn_mfma_f32_16x16x32_bf16(             \
            AFR[mf], bF[nf], acc[mh][mf][nf], 0, 0, 0);                        \
    __builtin_amdgcn_s_setprio(0);                                             \
  } while (0)

template <bool OUTF32>
__global__ __launch_bounds__(512, 2) void gemm256(const bf16* __restrict__ A,
                                                  const bf16* __restrict__ BT,
                                                  void* __restrict__ Cout,
                                                  int M, int N, int K) {
  __shared__ __align__(16) bf16 lds[49152];  // 96 KiB (3 x 32KB buffers)
  const int tid = threadIdx.x;
  const int w = tid >> 6, lane = tid & 63;
  const int quad = lane >> 4, lq = lane & 15;
  const int wmi = w >> 2, wni = w & 3;  // 2 (M) x 4 (N) waves

  // bijective XCD swizzle on flat 1-D grid (nwg % 8 == 0 here: 384, 256)
  const int nbx = N >> 8;
  const int nwg = (int)gridDim.x;
  const int flat = (int)blockIdx.x;
  const int swz = (flat & 7) * (nwg >> 3) + (flat >> 3);
  const int bm = (swz / nbx) << 8, bn = (swz % nbx) << 8;

  const bf16* aB = A + (size_t)bm * K;
  const bf16* bB = BT + (size_t)bn * K;
  const int NT = K >> 5;

  // staging geometry (chunk c = l*512 + tid; row = c>>2; swizzled chunk pos)
  const int sgc = (tid & 3) ^ ((tid >> 3) & 3);
  const int sr0 = tid >> 2, sr1 = sr0 + 128;
  const int am = wmi * 128, bnr = wni * 64;

  f32x4 acc[2][4][4] = {};

  // ---- prologue: stage tiles 0 and 1; retire tile 0 (4 stay in flight) ----
  STG_A(0, 0); STG_B(0, 0);
  STG_A(1, 1); STG_B(1, 1);
  asm volatile("s_waitcnt vmcnt(4)" ::: "memory");
  __builtin_amdgcn_s_barrier();

  int cb = 0;
  for (int t = 0; t < NT; ++t) {
    const int pb = (cb >= 1) ? cb - 1 : cb + 2;  // (cb+2)%3
    bf16x8 aF[4], bF[4], a2[4];

    // ---- phase 1: m0 ----
#pragma unroll
    for (int f = 0; f < 4; ++f) aF[f] = FRAG_A(cb, am + f * 16 + lq);
#pragma unroll
    for (int f = 0; f < 4; ++f) bF[f] = FRAG_B(cb, bnr + f * 16 + lq);
    if (t + 2 < NT) STG_A(pb, t + 2);
    __builtin_amdgcn_s_barrier();
    asm volatile("s_waitcnt lgkmcnt(0)" ::: "memory");
    MFMA_CLUSTER(0, aF);
    __builtin_amdgcn_s_barrier();

    // ---- phase 2: m1 ----
#pragma unroll
    for (int f = 0; f < 4; ++f) a2[f] = FRAG_A(cb, am + 64 + f * 16 + lq);
    if (t + 2 < NT) STG_B(pb, t + 2);
    if (t + 2 >= NT) {
      asm volatile("s_waitcnt vmcnt(0)" ::: "memory");
    } else {
      asm volatile("s_waitcnt vmcnt(4)" ::: "memory");
    }
    __builtin_amdgcn_s_barrier();
    asm volatile("s_waitcnt lgkmcnt(0)" ::: "memory");
    MFMA_CLUSTER(1, a2);
    __builtin_amdgcn_s_barrier();

    cb = (cb == 2) ? 0 : cb + 1;
  }

  // ---- epilogue: direct stores (16-lane contiguous segments per quad) ----
#pragma unroll
  for (int mh = 0; mh < 2; ++mh)
#pragma unroll
    for (int mf = 0; mf < 4; ++mf) {
      const size_t rbase =
          (size_t)(bm + am + mh * 64 + mf * 16 + quad * 4) * N;
#pragma unroll
      for (int nf = 0; nf < 4; ++nf) {
        const int col = bn + bnr + nf * 16 + lq;
        if (OUTF32) {
          float* gp = (float*)Cout + rbase + col;
#pragma unroll
          for (int r = 0; r < 4; ++r) gp[(size_t)r * N] = acc[mh][mf][nf][r];
        } else {
          bf16* gp = (bf16*)Cout + rbase + col;
#pragma unroll
          for (int r = 0; r < 4; ++r) gp[(size_t)r * N] = (bf16)acc[mh][mf][nf][r];
        }
      }
    }
}

// ---------------------------------------------------------------------------
// RoPE in-place on qkv buffer (cols 0..5119 = q,k heads). One pair per thread.
__global__ __launch_bounds__(256) void rope_kernel(bf16* __restrict__ qkv,
                                                   const float* __restrict__ fc,
                                                   const float* __restrict__ fs) {
  const int p = blockIdx.x * 256 + threadIdx.x;  // 0..2559 pair index
  const int tok = blockIdx.y;                    // 0..4095
  const int s = tok & (SEQ - 1);
  const int dh = p & 63;
  const float c = fc[s * 64 + dh], sn = fs[s * 64 + dh];
  bf16* ptr = qkv + (size_t)tok * QKVN + 2 * p;
  bf16x2 v = *(bf16x2*)ptr;
  const float x0 = (float)v[0], x1 = (float)v[1];
  bf16x2 o;
  o[0] = (bf16)(x0 * c - x1 * sn);
  o[1] = (bf16)(x0 * sn + x1 * c);
  *(bf16x2*)ptr = o;
}

// ---------------------------------------------------------------------------
// V transpose: qkv V columns -> vt[(b*8+g)*HD + d][s]
__global__ __launch_bounds__(256) void tp_v(const bf16* __restrict__ qkv,
                                            bf16* __restrict__ vt) {
  __shared__ bf16 t[32][33];
  const int tx = threadIdx.x, ty = threadIdx.y;  // 32 x 8
  const int s0 = blockIdx.x * 32, d0 = blockIdx.y * 32, bg = blockIdx.z;
  const bf16* src = qkv + (size_t)((bg >> 3) * SEQ) * QKVN + VCOFF + (bg & 7) * HD;
#pragma unroll
  for (int yy = 0; yy < 32; yy += 8)
    t[ty + yy][tx] = src[(size_t)(s0 + ty + yy) * QKVN + d0 + tx];
  __syncthreads();
  bf16* dst = vt + (size_t)bg * HD * SEQ;
#pragma unroll
  for (int yy = 0; yy < 32; yy += 8)
    dst[(size_t)(d0 + ty + yy) * SEQ + s0 + tx] = t[tx][ty + yy];
}

// ---------------------------------------------------------------------------
// Flash attention: S^T formulation, KVBLK=64, double-buffered K/V staging with
// counted vmcnt (tile t+1 loads stay in flight across all barriers of tile t).
// Raw s_barrier + manual lgkmcnt fences (no __syncthreads in-loop: its
// vmcnt(0) drain would kill the pipeline).
// LDS: lK[2][64x128] (K tile; P tile reuses current buf), lV[2][128x64] (V^T).
// Staging swizzle (both-sides XOR): K row=0..63, 16 chunks: LDS[r][p] holds
// global chunk p^(r&15); V^T row=0..127, 8 chunks: p^(r&7); P write/read
// uses ^(m&7) over 8 chunks.
#define ASTAGE(tt, bufsel)                                                     \
  do {                                                                         \
    const bf16* kb_ = kb0 + (size_t)((tt) * 64) * QKVN;                        \
    const bf16* vb_ = vt0 + (size_t)((tt) * 64);                               \
    _Pragma("unroll")                                                          \
    for (int i_ = 0; i_ < 4; ++i_) {                                           \
      const int c_ = i_ * 256 + tid;                                           \
      const int kr_ = c_ >> 4, kc_ = (c_ & 15) ^ (kr_ & 15);                   \
      GLL16(kb_ + (size_t)kr_ * QKVN + kc_ * 8,                                \
            lK + (bufsel) * 8192 + (i_ * 256 + w * 64) * 8);                   \
      const int vr_ = c_ >> 3, vc_ = (c_ & 7) ^ (vr_ & 7);                     \
      GLL16(vb_ + (size_t)vr_ * SEQ + vc_ * 8,                                 \
            lV + (bufsel) * 8192 + (i_ * 256 + w * 64) * 8);                   \
    }                                                                          \
  } while (0)

__global__ __launch_bounds__(256, 2) void attn_kernel(const bf16* __restrict__ qkv,
                                                      const bf16* __restrict__ vt,
                                                      bf16* __restrict__ aout) {
  __shared__ bf16 lK[2 * 64 * 128];  // 32KB: K tiles (double-buf); P in cur buf
  __shared__ bf16 lV[2 * 64 * 128];  // 32KB: V^T tiles (double-buf)
  const int tid = threadIdx.x;
  const int w = tid >> 6, lane = tid & 63;
  const int quad = lane >> 4, lq = lane & 15;
  const int qt = (int)gridDim.x - 1 - (int)blockIdx.x;  // heavy blocks first
  const int h = blockIdx.y, b = blockIdx.z;
  const int g = h >> 2;  // kv head (N_REP = 4)
  const int qbase = qt * 128;
  const int wm = w * 32;  // wave's 32 q rows

  const float scale = 0.08838834764831845f;  // 1/sqrt(128)
  const bf16* qp = qkv + (size_t)(b * SEQ + qbase) * QKVN + h * HD;
  bf16x8 qf[2][4];
#pragma unroll
  for (int i2 = 0; i2 < 2; ++i2)
#pragma unroll
    for (int kk = 0; kk < 4; ++kk) {
      bf16x8 v = *(const bf16x8*)(qp + (size_t)(wm + i2 * 16 + lq) * QKVN + kk * 32 + quad * 8);
#pragma unroll
      for (int e = 0; e < 8; ++e) v[e] = (bf16)((float)v[e] * scale);
      qf[i2][kk] = v;
    }

  float mi[2] = {NEG_BIG, NEG_BIG}, li[2] = {0.f, 0.f};
  f32x4 oacc[8][2] = {};  // O^T[d = ds*16+quad*4+r][m = wm+i2*16+lq]

  const bf16* kb0 = qkv + (size_t)(b * SEQ) * QKVN + KCOFF + g * HD;
  const bf16* vt0 = vt + (size_t)(b * NKV + g) * HD * SEQ;

  const int nt = 2 * qt + 2;  // number of 64-row KV tiles

  // prologue: stage tile 0 into buf 0
  ASTAGE(0, 0);

  for (int kt = 0; kt < nt; ++kt) {
    const int cb = kt & 1, ob = cb ^ 1;
    bf16* lKc = lK + cb * 8192;
    bf16* lVc = lV + cb * 8192;

    // issue next tile's staging, then wait only for tile kt's 8 loads
    if (kt + 1 < nt) {
      ASTAGE(kt + 1, ob);
      asm volatile("s_waitcnt vmcnt(8)" ::: "memory");
    } else {
      asm volatile("s_waitcnt vmcnt(0)" ::: "memory");
    }
    __builtin_amdgcn_s_barrier();  // B1: tile kt ready in buf cb

    // ---- QK^T -> S^T: sacc[i2][ns], n = ns*16+quad*4+r (tile-local) ----
    f32x4 sacc[2][4] = {};
#pragma unroll
    for (int kk = 0; kk < 4; ++kk) {
      bf16x8 kf[4];
#pragma unroll
      for (int ns = 0; ns < 4; ++ns) {
        const int n = ns * 16 + lq;
        kf[ns] = *(const bf16x8*)(lKc + n * 128 + (((kk * 4 + quad) ^ (n & 15))) * 8);
      }
#pragma unroll
      for (int i2 = 0; i2 < 2; ++i2)
#pragma unroll
        for (int ns = 0; ns < 4; ++ns)
          sacc[i2][ns] = __builtin_amdgcn_mfma_f32_16x16x32_bf16(kf[ns], qf[i2][kk], sacc[i2][ns], 0, 0, 0);
    }
    asm volatile("s_waitcnt lgkmcnt(0)" ::: "memory");
    __builtin_amdgcn_s_barrier();  // B2: lK[cb] reads done -> safe for P

    // ---- online softmax (per-lane state: column m = lq) ----
    const int rel = (kt - 2 * qt) * 64;  // tile n-offset minus qbase
#pragma unroll
    for (int i2 = 0; i2 < 2; ++i2) {
      const int m = wm + i2 * 16 + lq;
      if (rel > -64) {  // only last two tiles can touch the diagonal
#pragma unroll
        for (int ns = 0; ns < 4; ++ns)
#pragma unroll
          for (int r = 0; r < 4; ++r)
            if (rel + ns * 16 + quad * 4 + r > m) sacc[i2][ns][r] = NEG_BIG;
      }
      float mx = NEG_BIG;
#pragma unroll
      for (int ns = 0; ns < 4; ++ns)
#pragma unroll
        for (int r = 0; r < 4; ++r) mx = fmaxf(mx, sacc[i2][ns][r]);
      mx = fmaxf(mx, __shfl_xor(mx, 16));
      mx = fmaxf(mx, __shfl_xor(mx, 32));
      const float mnew = fmaxf(mi[i2], mx);
      const float al = __expf(mi[i2] - mnew);
      float rs = 0.f;
#pragma unroll
      for (int ns = 0; ns < 4; ++ns)
#pragma unroll
        for (int r = 0; r < 4; ++r) {
          const float e = __expf(sacc[i2][ns][r] - mnew);
          sacc[i2][ns][r] = e;
          rs += e;
        }
      rs += __shfl_xor(rs, 16);
      rs += __shfl_xor(rs, 32);
      li[i2] = li[i2] * al + rs;
      mi[i2] = mnew;
#pragma unroll
      for (int ds = 0; ds < 8; ++ds)
#pragma unroll
        for (int r = 0; r < 4; ++r) oacc[ds][i2][r] *= al;
    }

    // ---- write P [m][n] into lK[cb] (row stride 64, ^(m&7) chunk swizzle) --
#pragma unroll
    for (int i2 = 0; i2 < 2; ++i2) {
      const int m = wm + i2 * 16 + lq;
#pragma unroll
      for (int ns = 0; ns < 4; ++ns) {
        bf16x4 p4;
#pragma unroll
        for (int r = 0; r < 4; ++r) p4[r] = (bf16)sacc[i2][ns][r];
        const int n0 = ns * 16 + quad * 4;
        const int pc = (n0 >> 3) ^ (m & 7);
        *(bf16x4*)(lKc + m * 64 + pc * 8 + (n0 & 7)) = p4;
      }
    }
    asm volatile("s_waitcnt lgkmcnt(0)" ::: "memory");
    __builtin_amdgcn_s_barrier();  // B3: P visible

    // ---- PV: O^T[d][m] += MFMA(A = V^T, B = P), contraction = 64 ----
#pragma unroll
    for (int gg = 0; gg < 2; ++gg) {
      bf16x8 pf[2];
#pragma unroll
      for (int i2 = 0; i2 < 2; ++i2) {
        const int m = wm + i2 * 16 + lq;
        pf[i2] = *(const bf16x8*)(lKc + m * 64 + (((gg * 4 + quad) ^ (m & 7))) * 8);
      }
#pragma unroll
      for (int ds = 0; ds < 8; ++ds) {
        const int d = ds * 16 + lq;
        bf16x8 vf = *(const bf16x8*)(lVc + d * 64 + (((gg * 4 + quad) ^ (d & 7))) * 8);
#pragma unroll
        for (int i2 = 0; i2 < 2; ++i2)
          oacc[ds][i2] = __builtin_amdgcn_mfma_f32_16x16x32_bf16(vf, pf[i2], oacc[ds][i2], 0, 0, 0);
      }
    }
    asm volatile("s_waitcnt lgkmcnt(0)" ::: "memory");
    __builtin_amdgcn_s_barrier();  // B4: buf cb reads done before re-stage
  }

  // ---- epilogue: O^T/l -> LDS [m][128] (32KB = both lK bufs) -> global ----
#pragma unroll
  for (int ds = 0; ds < 8; ++ds)
#pragma unroll
    for (int i2 = 0; i2 < 2; ++i2) {
      const int m = wm + i2 * 16 + lq;
      const float inv = 1.0f / li[i2];
      bf16x4 o4;
#pragma unroll
      for (int r = 0; r < 4; ++r) o4[r] = (bf16)(oacc[ds][i2][r] * inv);
      const int d0 = ds * 16 + quad * 4;
      const int pc = (d0 >> 3) ^ (m & 15);
      *(bf16x4*)(lK + m * 128 + pc * 8 + (d0 & 7)) = o4;
    }
  __syncthreads();
  {
    const int m = tid >> 1, hf = tid & 1;
    bf16* ob = aout + (size_t)(b * SEQ + qbase + m) * (NH * HD) + h * HD + hf * 64;
#pragma unroll
    for (int c = 0; c < 8; ++c) {
      const int lc = hf * 8 + c;
      bf16x8 vv = *(const bf16x8*)(lK + m * 128 + ((lc ^ (m & 15))) * 8);
      *(bf16x8*)(ob + c * 8) = vv;
    }
  }
}

// ---------------------------------------------------------------------------
extern "C" void kernel_launch(void* const* d_in, const int* in_sizes, int n_in,
                              void* d_out, int out_size, void* d_ws, size_t ws_size,
                              hipStream_t stream) {
  (void)in_sizes; (void)n_in; (void)out_size; (void)ws_size;
  const float* x  = (const float*)d_in[0];
  const float* fc = (const float*)d_in[2];
  const float* fs = (const float*)d_in[3];
  const float* wq = (const float*)d_in[6];
  const float* wk = (const float*)d_in[7];
  const float* wv = (const float*)d_in[8];
  const float* wo = (const float*)d_in[9];

  char* ws = (char*)d_ws;
  // layout: [0,48MB) wT (wqkv^T; later wo^T in [0,32MB) + vt in [32,40MB))
  //         [48,80MB) xb (later attn out) | [80,128MB) qkv
  bf16* wT   = (bf16*)ws;
  bf16* vtb  = (bf16*)(ws + 33554432);
  bf16* xb   = (bf16*)(ws + 50331648);
  bf16* qkvb = (bf16*)(ws + 83886080);
  float* outp = (float*)d_out;

  const dim3 tb(32, 8);
  transpose_cvt3<<<dim3(QKVN / 32, DIM / 32), tb, 0, stream>>>(wq, wk, wv, wT);
  cvt_f32_bf16<<<(NTOK * DIM) / 1024, 256, 0, stream>>>(x, xb);
  gemm256<false><<<dim3((QKVN / 256) * (NTOK / 256)), 512, 0, stream>>>(xb, wT, qkvb, NTOK, QKVN, DIM);
  rope_kernel<<<dim3(10, NTOK), 256, 0, stream>>>(qkvb, fc, fs);
  tp_v<<<dim3(SEQ / 32, HD / 32, BATCH * NKV), tb, 0, stream>>>(qkvb, vtb);
  transpose_cvt<<<dim3(DIM / 32, (NH * HD) / 32), tb, 0, stream>>>(wo, wT, NH * HD, DIM);
  attn_kernel<<<dim3(SEQ / 128, NH, BATCH), 256, 0, stream>>>(qkvb, vtb, xb);
  gemm256<true><<<dim3((DIM / 256) * (NTOK / 256)), 512, 0, stream>>>(xb, wT, outp, NTOK, DIM, NH * HD);
}